// Round 8
// baseline (15963.367 us; speedup 1.0000x reference)
//
#include <hip/hip_runtime.h>
#include <math.h>

#define TT 2048
#define NSTEP 2053           // per-set steps: 2048 + 4 fill + 1 head drain
#define NPH (2 * NSTEP)      // interleaved phases (2 batch-sets)

typedef _Float16 half2v __attribute__((ext_vector_type(2)));
typedef _Float16 half8v __attribute__((ext_vector_type(8)));

#if defined(__has_builtin)
#if __has_builtin(__builtin_amdgcn_fdot2)
#define HAVE_FDOT2 1
#endif
#endif

__device__ __forceinline__ float fdot2f(half2v a, half2v b, float c) {
#ifdef HAVE_FDOT2
    return __builtin_amdgcn_fdot2(a, b, c, false);
#else
    return c + (float)a.x * (float)b.x + (float)a.y * (float)b.y;
#endif
}
__device__ __forceinline__ half2v h2at(half8v v, int m) {
    half2v r; r.x = v[2 * m]; r.y = v[2 * m + 1]; return r;
}
__device__ __forceinline__ float sigf(float x) { return 1.0f / (1.0f + __expf(-x)); }
__device__ __forceinline__ float tanh_f(float x) {
    float t = __expf(fminf(2.0f * x, 30.0f));
    return (t - 1.0f) / (t + 1.0f);
}

// ---- d_ws layout (bytes) ----
// [0, 524288)        board: u32 [2 set][2 parity][32 group][512 h] (2 batch fp16/u32)
// [524288, +65536)   flags: int [2 set][32 group][8 member] stride 16 ints
#define FLAGS_BOFF 524288
#define ZERO_F4    36864

// ---- dynamic LDS (halves) ----
#define K1STR 264
#define K2STR 392
#define K3STR 200
#define K4STR 104
#define K5STR 72
#define XSTR  520
#define W1_OFF 0
#define W2_OFF 33792
#define W3_OFF 58880
#define W4_OFF 65280
#define W5_OFF 66944
#define X_OFF  67520
#define LDS_BYTES 139264

__global__ __launch_bounds__(256)
void prep_zero(float4* ws) {
    int idx = blockIdx.x * 256 + threadIdx.x;
    if (idx < ZERO_F4) ws[idx] = make_float4(0.f, 0.f, 0.f, 0.f);
}

// One layer slice for one batch-set (2 batches). RG h-units, rows r = rg + RG*i.
// KG-way k-split, J iters of 8k. Butterfly -> all lanes hold 8 sums; lanes kg<2
// own batch phb+kg (c in register); lane kg==0 stores packed u32 (2 fp16) to board.
template<int RG, int KG, int J, int KOFF, int KSTR, int HBASE, bool ISL1>
__device__ __forceinline__ void layer_ph(
    const _Float16* __restrict__ W, const float* __restrict__ bias,
    const _Float16* __restrict__ Xs,
    unsigned int* __restrict__ bdst,
    const float* __restrict__ w1xl, const float* __restrict__ xinb, int xoff,
    float& cpriv, int u, int lane, int m, int phb)
{
    const int kg = u & (KG - 1);
    const int rg = u / KG;

    float acc[4][2];
#pragma unroll
    for (int i = 0; i < 4; ++i) { acc[i][0] = 0.f; acc[i][1] = 0.f; }

#pragma unroll
    for (int jj = 0; jj < J; ++jj) {
        const int kk = kg * 8 + jj * (KG * 8);
        half8v xv[2], wv[4];
        xv[0] = *(const half8v*)(Xs + (phb + 0) * XSTR + KOFF + kk);
        xv[1] = *(const half8v*)(Xs + (phb + 1) * XSTR + KOFF + kk);
#pragma unroll
        for (int i = 0; i < 4; ++i)
            wv[i] = *(const half8v*)(W + (rg + RG * i) * KSTR + kk);
#pragma unroll
        for (int i = 0; i < 4; ++i)
#pragma unroll
            for (int j = 0; j < 2; ++j)
#pragma unroll
                for (int mm = 0; mm < 4; ++mm)
                    acc[i][j] = fdot2f(h2at(wv[i], mm), h2at(xv[j], mm), acc[i][j]);
    }

#pragma unroll
    for (int d = 1; d < KG; d <<= 1)
#pragma unroll
        for (int i = 0; i < 4; ++i)
#pragma unroll
            for (int j = 0; j < 2; ++j)
                acc[i][j] += __shfl_xor(acc[i][j], d, 64);

    float h = 0.f;
    if (kg < 2) {
        const int j = kg;
        float g0 = acc[0][j] + bias[rg];
        float g1 = acc[1][j] + bias[rg + RG];
        float g2 = acc[2][j] + bias[rg + 2 * RG];
        float g3 = acc[3][j] + bias[rg + 3 * RG];
        if (ISL1) {
            float xt = xinb[(phb + j) * 64 + xoff];
            g0 = fmaf(w1xl[rg], xt, g0);
            g1 = fmaf(w1xl[rg + RG], xt, g1);
            g2 = fmaf(w1xl[rg + 2 * RG], xt, g2);
            g3 = fmaf(w1xl[rg + 3 * RG], xt, g3);
        }
        float ig = sigf(g0), fg = sigf(g1), gg = tanh_f(g2), og = sigf(g3);
        float cn = fmaf(fg, cpriv, ig * gg);
        cpriv = cn;
        h = og * tanh_f(cn);
    }
    union { _Float16 hf; unsigned short us; } cv;
    cv.hf = (_Float16)h;
    const int base = lane & ~(KG - 1);
    unsigned int lo = (unsigned short)__shfl((int)cv.us, base + 0, 64);
    unsigned int hi = (unsigned short)__shfl((int)cv.us, base + 1, 64);
    if (kg == 0)
        __hip_atomic_store(bdst + (HBASE + m * RG + rg), lo | (hi << 16),
                           __ATOMIC_RELAXED, __HIP_MEMORY_SCOPE_AGENT);
}

__global__ __launch_bounds__(512)
void lstm_ph(const float* __restrict__ inp,
             const float* __restrict__ w1ih, const float* __restrict__ w1hh,
             const float* __restrict__ b1ih, const float* __restrict__ b1hh,
             const float* __restrict__ w2ih, const float* __restrict__ w2hh,
             const float* __restrict__ b2ih, const float* __restrict__ b2hh,
             const float* __restrict__ w3ih, const float* __restrict__ w3hh,
             const float* __restrict__ b3ih, const float* __restrict__ b3hh,
             const float* __restrict__ w4ih, const float* __restrict__ w4hh,
             const float* __restrict__ b4ih, const float* __restrict__ b4hh,
             const float* __restrict__ w5ih, const float* __restrict__ w5hh,
             const float* __restrict__ b5ih, const float* __restrict__ b5hh,
             const float* __restrict__ wlin, const float* __restrict__ blin,
             float* __restrict__ out, char* __restrict__ wsb)
{
    extern __shared__ __align__(16) _Float16 smem[];
    _Float16* Wl1 = smem + W1_OFF;
    _Float16* Wl2 = smem + W2_OFF;
    _Float16* Wl3 = smem + W3_OFF;
    _Float16* Wl4 = smem + W4_OFF;
    _Float16* Wl5 = smem + W5_OFF;
    _Float16* Xs  = smem + X_OFF;

    __shared__ float Xin[2 * 256];             // double-buffered [buf][4 b][64 t]
    __shared__ float bias1[128], bias2[64], bias3[32], bias4[16], bias5[8];
    __shared__ float w1xl[128], wlin_s[16], blin_s;

    const int tid = threadIdx.x;
    const int g = blockIdx.x & 31;     // group (same mod-8 class -> XCD heuristic)
    const int m = blockIdx.x >> 5;     // member 0..7
    const int lane = tid & 63;

    // ---- init: stage fp16 weight shards into LDS (read-once) ----
    for (int idx = tid; idx < 128 * 256; idx += 512) {
        int r = idx >> 8, k = idx & 255;
        int i = r >> 5, rg = r & 31;
        int grow = i * 256 + m * 32 + rg;
        Wl1[r * K1STR + k] = (_Float16)w1hh[grow * 256 + k];
    }
    for (int idx = tid; idx < 64 * 384; idx += 512) {
        int r = idx / 384, k = idx - r * 384;
        int i = r >> 4, rg = r & 15;
        int grow = i * 128 + m * 16 + rg;
        float v = (k < 256) ? w2ih[grow * 256 + k] : w2hh[grow * 128 + (k - 256)];
        Wl2[r * K2STR + k] = (_Float16)v;
    }
    for (int idx = tid; idx < 32 * 192; idx += 512) {
        int r = idx / 192, k = idx - r * 192;
        int i = r >> 3, rg = r & 7;
        int grow = i * 64 + m * 8 + rg;
        float v = (k < 128) ? w3ih[grow * 128 + k] : w3hh[grow * 64 + (k - 128)];
        Wl3[r * K3STR + k] = (_Float16)v;
    }
    for (int idx = tid; idx < 16 * 96; idx += 512) {
        int r = idx / 96, k = idx - r * 96;
        int i = r >> 2, rg = r & 3;
        int grow = i * 32 + m * 4 + rg;
        float v = (k < 64) ? w4ih[grow * 64 + k] : w4hh[grow * 32 + (k - 64)];
        Wl4[r * K4STR + k] = (_Float16)v;
    }
    for (int idx = tid; idx < 8 * 64; idx += 512) {      // L5 k-padded to 64
        int r = idx >> 6, k = idx & 63;
        int i = r >> 1, rg = r & 1;
        int grow = i * 16 + m * 2 + rg;
        float v = (k < 32) ? w5ih[grow * 32 + k]
                           : (k < 48 ? w5hh[grow * 16 + (k - 32)] : 0.f);
        Wl5[r * K5STR + k] = (_Float16)v;
    }
    for (int idx = tid; idx < 4 * XSTR; idx += 512) Xs[idx] = (_Float16)0.f;

    if (tid < 128) {
        int i = tid >> 5, rg = tid & 31;
        int grow = i * 256 + m * 32 + rg;
        bias1[tid] = b1ih[grow] + b1hh[grow];
        w1xl[tid] = w1ih[grow];
    } else if (tid < 192) {
        int u = tid - 128; int i = u >> 4, rg = u & 15;
        int grow = i * 128 + m * 16 + rg;
        bias2[u] = b2ih[grow] + b2hh[grow];
    } else if (tid < 224) {
        int u = tid - 192; int i = u >> 3, rg = u & 7;
        int grow = i * 64 + m * 8 + rg;
        bias3[u] = b3ih[grow] + b3hh[grow];
    } else if (tid < 240) {
        int u = tid - 224; int i = u >> 2, rg = u & 3;
        int grow = i * 32 + m * 4 + rg;
        bias4[u] = b4ih[grow] + b4hh[grow];
    } else if (tid < 248) {
        int u = tid - 240; int i = u >> 1, rg = u & 1;
        int grow = i * 16 + m * 2 + rg;
        bias5[u] = b5ih[grow] + b5hh[grow];
    } else if (tid < 264) {
        wlin_s[tid - 248] = wlin[tid - 248];
    } else if (tid == 264) {
        blin_s = blin[0];
    }
    if (tid >= 448) {                          // input chunk 0 -> buf 0
        int u = tid - 448, b = u >> 4, t4 = (u & 15) << 2;
        *(float4*)(Xin + b * 64 + t4) =
            *(const float4*)(inp + (size_t)(g * 4 + b) * TT + t4);
    }
    __syncthreads();

    unsigned int* board = (unsigned int*)wsb;
    int* flags = (int*)(wsb + FLAGS_BOFF);
    float cpriv[2] = {0.f, 0.f};

    for (int p = 0; p < NPH; ++p) {
        const int ph = p & 1;          // batch-set
        const int s = p >> 1;          // this set's step
        const int phb = ph * 2;

        // ---- poll + prefetch raw board data for phase p+1 (other set) ----
        // Flags for set ph^1 step s2 were posted at end of phase p-1 -> near-zero
        // wait; the data loads fly during this phase's compute. Per-wave gating,
        // no extra barrier. No fences anywhere (ordering via syncthreads vmcnt drain).
        unsigned int rawv = 0;
        if (p + 1 < NPH) {
            const int ph2 = ph ^ 1;
            const int s2 = (p + 1) >> 1;
            if (lane < 8) {
                const int* fp = flags + ((ph2 * 32 + g) * 8 + lane) * 16;
                while (__hip_atomic_load(fp, __ATOMIC_RELAXED,
                                         __HIP_MEMORY_SCOPE_AGENT) < s2)
                    __builtin_amdgcn_s_sleep(1);
            }
            if (tid < 496) {
                const unsigned int* bsrc =
                    board + (size_t)(((ph2 * 2 + ((s2 - 1) & 1)) * 32 + g)) * 512;
                rawv = __hip_atomic_load(bsrc + tid, __ATOMIC_RELAXED,
                                         __HIP_MEMORY_SCOPE_AGENT);
            }
        }

        // ---- input chunk prefetch (double-buffered, 32 phases of slack) ----
        if (ph == 0 && (s & 63) == 48 && (s + 16) < TT && tid >= 448) {
            int T0 = (s & ~63) + 64;
            int u = tid - 448, b = u >> 4, t4 = (u & 15) << 2;
            *(float4*)(Xin + (((T0 >> 6) & 1) * 256) + b * 64 + t4) =
                *(const float4*)(inp + (size_t)(g * 4 + b) * TT + T0 + t4);
        }

        const float* xinb = Xin + (((s >> 6) & 1) * 256);
        unsigned int* bdst = board + (size_t)(((ph * 2 + (s & 1)) * 32 + g)) * 512;
        const int xoff = s & 63;

        // ---- diagonal layer pipeline on disjoint wave ranges ----
        if (tid < 256) {
            if (s < TT)
                layer_ph<32, 8, 4, 0, K1STR, 0, true>(
                    Wl1, bias1, Xs, bdst, w1xl, xinb, xoff, cpriv[ph], tid, lane, m, phb);
        } else if (tid < 384) {
            if (s >= 1 && s <= TT)
                layer_ph<16, 8, 6, 0, K2STR, 256, false>(
                    Wl2, bias2, Xs, bdst, w1xl, xinb, 0, cpriv[ph], tid - 256, lane, m, phb);
        } else if (tid < 448) {
            if (s >= 2 && s <= TT + 1)
                layer_ph<8, 8, 3, 256, K3STR, 384, false>(
                    Wl3, bias3, Xs, bdst, w1xl, xinb, 0, cpriv[ph], tid - 384, lane, m, phb);
        } else if (tid < 464) {
            if (s >= 3 && s <= TT + 2)
                layer_ph<4, 4, 3, 384, K4STR, 448, false>(
                    Wl4, bias4, Xs, bdst, w1xl, xinb, 0, cpriv[ph], tid - 448, lane, m, phb);
        } else if (tid < 472) {
            if (s >= 4 && s <= TT + 3)
                layer_ph<2, 4, 2, 448, K5STR, 480, false>(
                    Wl5, bias5, Xs, bdst, w1xl, xinb, 0, cpriv[ph], tid - 464, lane, m, phb);
        } else if (tid < 474) {
            if (m == 0 && s >= 5) {
                int j = tid - 472;                 // batch phb+j
                float a = blin_s;
#pragma unroll
                for (int k = 0; k < 16; ++k)
                    a = fmaf((float)Xs[(phb + j) * XSTR + 480 + k], wlin_s[k], a);
                out[(size_t)(g * 4 + phb + j) * TT + (s - 5)] = a;
            }
        }

        // ---- unpack prefetched data for the other set (disjoint Xs rows) ----
        if (p + 1 < NPH && tid < 496) {
            unsigned short* Xu = (unsigned short*)Xs;
            const int phb2 = (ph ^ 1) * 2;
            Xu[(phb2 + 0) * XSTR + tid] = (unsigned short)(rawv & 0xffffu);
            Xu[(phb2 + 1) * XSTR + tid] = (unsigned short)(rawv >> 16);
        }

        // ---- end of phase: drain board stores + publish flag (no fence) ----
        __syncthreads();
        if (tid == 0)
            __hip_atomic_store(flags + ((ph * 32 + g) * 8 + m) * 16, s + 1,
                               __ATOMIC_RELAXED, __HIP_MEMORY_SCOPE_AGENT);
    }
}

extern "C" void kernel_launch(void* const* d_in, const int* in_sizes, int n_in,
                              void* d_out, int out_size, void* d_ws, size_t ws_size,
                              hipStream_t stream) {
    const float* p[23];
    for (int i = 0; i < 23 && i < n_in; ++i) p[i] = (const float*)d_in[i];

    (void)hipFuncSetAttribute((const void*)lstm_ph,
                              hipFuncAttributeMaxDynamicSharedMemorySize,
                              LDS_BYTES);

    prep_zero<<<dim3((ZERO_F4 + 255) / 256), dim3(256), 0, stream>>>((float4*)d_ws);

    // ~136KB dynamic + ~3.3KB static LDS -> 1 block/CU; grid 256 = CU count ->
    // all 32 groups x 8 members co-resident (required for the flag protocol).
    lstm_ph<<<dim3(256), dim3(512), LDS_BYTES, stream>>>(
        p[0],
        p[1],  p[2],  p[3],  p[4],
        p[5],  p[6],  p[7],  p[8],
        p[9],  p[10], p[11], p[12],
        p[13], p[14], p[15], p[16],
        p[17], p[18], p[19], p[20],
        p[21], p[22],
        (float*)d_out, (char*)d_ws);
}

// Round 9
// 14237.538 us; speedup vs baseline: 1.1212x; 1.1212x over previous
//
#include <hip/hip_runtime.h>
#include <math.h>

#define TT 2048
#define NLOOP 2053   // 2048 + 5 (L2..head diagonal offsets)

typedef _Float16 half2v __attribute__((ext_vector_type(2)));
typedef _Float16 half8v __attribute__((ext_vector_type(8)));

#if defined(__has_builtin)
#if __has_builtin(__builtin_amdgcn_fdot2)
#define HAVE_FDOT2 1
#endif
#endif

__device__ __forceinline__ float fdot2f(half2v a, half2v b, float c) {
#ifdef HAVE_FDOT2
    return __builtin_amdgcn_fdot2(a, b, c, false);
#else
    return c + (float)a.x * (float)b.x + (float)a.y * (float)b.y;
#endif
}
__device__ __forceinline__ half2v h2at(half8v v, int m) {
    half2v r; r.x = v[2 * m]; r.y = v[2 * m + 1]; return r;
}
__device__ __forceinline__ float sigf(float x) { return 1.0f / (1.0f + __expf(-x)); }
__device__ __forceinline__ float tanh_f(float x) {
    float t = __expf(fminf(2.0f * x, 30.0f));
    return (t - 1.0f) / (t + 1.0f);
}

// ---- d_ws layout (bytes) ----
// [0, 1048576)        board: u64 [8 slot][32 group][512 h] (u64 = 4 batch fp16)
// [1048576, +131072)  flags: int [(g*8+cls)*8+m]*16  (cls = wave id 0..7, monotone)
#define FLAGS_BOFF 1048576
#define ZERO_F4    73728      // float4 covering board+flags exactly

// ---- dynamic LDS (halves) ----
#define K1STR 264
#define K2STR 392
#define K3STR 200
#define K4STR 136            // L4 K padded 96->128 (+stride pad)
#define K5STR 72             // L5 K padded 48->64 (+stride pad)
#define W1_OFF 0             // 128 x 264
#define W2_OFF 33792         // 64 x 392
#define W3_OFF 58880         // 32 x 200
#define W4_OFF 65280         // 16 x 136
#define W5_OFF 67456         // 8 x 72
#define XL1_OFF 68032        // + w*1056,  [4][264]  (L1 waves 0..3 private h1)
#define XL2_OFF 72256        // + w2*1568, [4][392]  (L2 waves private h1|h2)
#define XL3_OFF 75392        // [4][200]             (w6: h2|h3)
#define XL4_OFF 76192        // [4][136]             (w7: h3|h4, zero-padded)
#define XL5_OFF 76736        // [4][72]              (w7: h4|h5, zero-padded)
#define XH5_OFF 77024        // [4][24]              (w6 head: h5)
#define LDS_HALVES 77120
#define LDS_BYTES  154240

__global__ __launch_bounds__(256)
void prep_zero(float4* ws) {
    int idx = blockIdx.x * 256 + threadIdx.x;
    if (idx < ZERO_F4) ws[idx] = make_float4(0.f, 0.f, 0.f, 0.f);
}

// Ballot-wait: lanes [0, ncls*8) each poll one flag (class cls_lo + lane>>3,
// member lane&7) until >= target. Relaxed loads only, no fences.
__device__ __forceinline__ void wait_cls(const int* flags, int g, int cls_lo,
                                         int ncls, int target, int lane) {
    bool need = lane < ncls * 8;
    const int* fp = flags;
    if (need) {
        int cls = cls_lo + (lane >> 3), mm = lane & 7;
        fp = flags + ((g * 8 + cls) * 8 + mm) * 16;
    }
    for (;;) {
        bool ok = !need ||
            (__hip_atomic_load(fp, __ATOMIC_RELAXED, __HIP_MEMORY_SCOPE_AGENT) >= target);
        if (__all(ok)) break;
        __builtin_amdgcn_s_sleep(1);
    }
    asm volatile("" ::: "memory");   // no hoisting of board loads above the poll
}

// Stage NU board u64s (4 batches packed) into private X region [4][STR].
template<int NU, int STR>
__device__ __forceinline__ void stage(const unsigned long long* __restrict__ bsrc,
                                      int h0, int k0, unsigned short* __restrict__ Xu) {
#pragma unroll
    for (int i = 0; i < NU; ++i) {
        unsigned long long v = __hip_atomic_load(bsrc + h0 + i, __ATOMIC_RELAXED,
                                                 __HIP_MEMORY_SCOPE_AGENT);
        int k = k0 + i;
        Xu[0 * STR + k] = (unsigned short)v;
        Xu[1 * STR + k] = (unsigned short)(v >> 16);
        Xu[2 * STR + k] = (unsigned short)(v >> 32);
        Xu[3 * STR + k] = (unsigned short)(v >> 48);
    }
}

// Per-wave layer slice (R6-proven math): RG units, rows r = rg + RG*i (gate i),
// KG-way k-split, J iters of 8k. Butterfly over kg; lanes kg<4 own batch kg
// (c in register); lane kg==0 stores packed u64 to board. No fences.
template<int RG, int KG, int J, int KSTR, int XSTRL, int HBASE, bool ISL1>
__device__ __forceinline__ void layer_pw(
    const _Float16* __restrict__ W, const float* __restrict__ bias,
    const _Float16* __restrict__ Xw, unsigned long long* __restrict__ bdst,
    const float* __restrict__ w1xl, float xt, float& cpriv,
    int u, int lane, int m)
{
    const int kg = u & (KG - 1);
    const int rg = u / KG;

    float acc[4][4];
#pragma unroll
    for (int i = 0; i < 4; ++i)
#pragma unroll
        for (int j = 0; j < 4; ++j) acc[i][j] = 0.f;

#pragma unroll
    for (int jj = 0; jj < J; ++jj) {
        const int kk = kg * 8 + jj * (KG * 8);
        half8v xv[4], wv[4];
#pragma unroll
        for (int j = 0; j < 4; ++j)
            xv[j] = *(const half8v*)(Xw + j * XSTRL + kk);
#pragma unroll
        for (int i = 0; i < 4; ++i)
            wv[i] = *(const half8v*)(W + (rg + RG * i) * KSTR + kk);
#pragma unroll
        for (int i = 0; i < 4; ++i)
#pragma unroll
            for (int j = 0; j < 4; ++j)
#pragma unroll
                for (int mm = 0; mm < 4; ++mm)
                    acc[i][j] = fdot2f(h2at(wv[i], mm), h2at(xv[j], mm), acc[i][j]);
    }

#pragma unroll
    for (int d = 1; d < KG; d <<= 1)
#pragma unroll
        for (int i = 0; i < 4; ++i)
#pragma unroll
            for (int j = 0; j < 4; ++j)
                acc[i][j] += __shfl_xor(acc[i][j], d, 64);

    float h = 0.f;
    if (kg < 4) {
        const int j = kg;
        float g0 = acc[0][j] + bias[rg];
        float g1 = acc[1][j] + bias[rg + RG];
        float g2 = acc[2][j] + bias[rg + 2 * RG];
        float g3 = acc[3][j] + bias[rg + 3 * RG];
        if (ISL1) {
            g0 = fmaf(w1xl[rg], xt, g0);
            g1 = fmaf(w1xl[rg + RG], xt, g1);
            g2 = fmaf(w1xl[rg + 2 * RG], xt, g2);
            g3 = fmaf(w1xl[rg + 3 * RG], xt, g3);
        }
        float ig = sigf(g0), fg = sigf(g1), gg = tanh_f(g2), og = sigf(g3);
        float cn = fmaf(fg, cpriv, ig * gg);
        cpriv = cn;
        h = og * tanh_f(cn);
    }
    union { _Float16 hf; unsigned short us; } cv;
    cv.hf = (_Float16)h;
    const int base = lane & ~(KG - 1);
    unsigned long long p0 = (unsigned short)__shfl((int)cv.us, base + 0, 64);
    unsigned long long p1 = (unsigned short)__shfl((int)cv.us, base + 1, 64);
    unsigned long long p2 = (unsigned short)__shfl((int)cv.us, base + 2, 64);
    unsigned long long p3 = (unsigned short)__shfl((int)cv.us, base + 3, 64);
    if (kg == 0) {
        unsigned long long packed = p0 | (p1 << 16) | (p2 << 32) | (p3 << 48);
        __hip_atomic_store(bdst + (HBASE + m * RG + rg), packed,
                           __ATOMIC_RELAXED, __HIP_MEMORY_SCOPE_AGENT);
    }
}

// Board slot helpers: writer at counter n uses slot n&7; all reads use (n-1)&7.
// Overwrite safety (depth 8): producers throttle on consumer-class flags >= n-3
// every 4 steps; consumers lag <= 4 < 8.  Deadlock-free: every poll targets
// completion of counter n-1, and every wave posts its flag every counter.
__global__ __launch_bounds__(512)
void lstm_pw(const float* __restrict__ inp,
             const float* __restrict__ w1ih, const float* __restrict__ w1hh,
             const float* __restrict__ b1ih, const float* __restrict__ b1hh,
             const float* __restrict__ w2ih, const float* __restrict__ w2hh,
             const float* __restrict__ b2ih, const float* __restrict__ b2hh,
             const float* __restrict__ w3ih, const float* __restrict__ w3hh,
             const float* __restrict__ b3ih, const float* __restrict__ b3hh,
             const float* __restrict__ w4ih, const float* __restrict__ w4hh,
             const float* __restrict__ b4ih, const float* __restrict__ b4hh,
             const float* __restrict__ w5ih, const float* __restrict__ w5hh,
             const float* __restrict__ b5ih, const float* __restrict__ b5hh,
             const float* __restrict__ wlin, const float* __restrict__ blin,
             float* __restrict__ out, char* __restrict__ wsb)
{
    extern __shared__ __align__(16) _Float16 smem[];
    _Float16* Wl1 = smem + W1_OFF;
    _Float16* Wl2 = smem + W2_OFF;
    _Float16* Wl3 = smem + W3_OFF;
    _Float16* Wl4 = smem + W4_OFF;
    _Float16* Wl5 = smem + W5_OFF;

    __shared__ float bias1[128], bias2[64], bias3[32], bias4[16], bias5[8];
    __shared__ float w1xl[128], wlin_s[16], blin_s;

    const int tid = threadIdx.x;
    const int g = blockIdx.x & 31;     // group: members {g, g+32, ...} share XCD class
    const int m = blockIdx.x >> 5;     // member 0..7
    const int w = tid >> 6;            // wave id = flag class
    const int lane = tid & 63;

    // ---- init: stage fp16 weight shards into LDS ----
    for (int idx = tid; idx < 128 * 256; idx += 512) {
        int r = idx >> 8, k = idx & 255;
        int i = r >> 5, rg = r & 31;
        int grow = i * 256 + m * 32 + rg;
        Wl1[r * K1STR + k] = (_Float16)w1hh[grow * 256 + k];
    }
    for (int idx = tid; idx < 64 * 384; idx += 512) {
        int r = idx / 384, k = idx - r * 384;
        int i = r >> 4, rg = r & 15;
        int grow = i * 128 + m * 16 + rg;
        float v = (k < 256) ? w2ih[grow * 256 + k] : w2hh[grow * 128 + (k - 256)];
        Wl2[r * K2STR + k] = (_Float16)v;
    }
    for (int idx = tid; idx < 32 * 192; idx += 512) {
        int r = idx / 192, k = idx - r * 192;
        int i = r >> 3, rg = r & 7;
        int grow = i * 64 + m * 8 + rg;
        float v = (k < 128) ? w3ih[grow * 128 + k] : w3hh[grow * 64 + (k - 128)];
        Wl3[r * K3STR + k] = (_Float16)v;
    }
    for (int idx = tid; idx < 16 * 136; idx += 512) {
        int r = idx / 136, k = idx - r * 136;
        int grow = (r >> 2) * 32 + m * 4 + (r & 3);
        float v = (k < 64) ? w4ih[grow * 64 + k]
                           : (k < 96 ? w4hh[grow * 32 + (k - 64)] : 0.f);
        Wl4[r * K4STR + k] = (_Float16)v;
    }
    for (int idx = tid; idx < 8 * 72; idx += 512) {
        int r = idx / 72, k = idx - r * 72;
        int grow = (r >> 1) * 16 + m * 2 + (r & 1);
        float v = (k < 32) ? w5ih[grow * 32 + k]
                           : (k < 48 ? w5hh[grow * 16 + (k - 32)] : 0.f);
        Wl5[r * K5STR + k] = (_Float16)v;
    }
    for (int idx = tid; idx < LDS_HALVES - XL1_OFF; idx += 512)
        smem[XL1_OFF + idx] = (_Float16)0.f;   // X regions zero (incl. K pads)

    if (tid < 128) {
        int i = tid >> 5, rg = tid & 31;
        int grow = i * 256 + m * 32 + rg;
        bias1[tid] = b1ih[grow] + b1hh[grow];
        w1xl[tid] = w1ih[grow];
    } else if (tid < 192) {
        int u = tid - 128; int grow = (u >> 4) * 128 + m * 16 + (u & 15);
        bias2[u] = b2ih[grow] + b2hh[grow];
    } else if (tid < 224) {
        int u = tid - 192; int grow = (u >> 3) * 64 + m * 8 + (u & 7);
        bias3[u] = b3ih[grow] + b3hh[grow];
    } else if (tid < 240) {
        int u = tid - 224; int grow = (u >> 2) * 32 + m * 4 + (u & 3);
        bias4[u] = b4ih[grow] + b4hh[grow];
    } else if (tid < 248) {
        int u = tid - 240; int grow = (u >> 1) * 16 + m * 2 + (u & 1);
        bias5[u] = b5ih[grow] + b5hh[grow];
    } else if (tid < 264) {
        wlin_s[tid - 248] = wlin[tid - 248];
    } else if (tid == 264) {
        blin_s = blin[0];
    }
    __syncthreads();   // last barrier — main loops are wave-autonomous

    unsigned long long* board = (unsigned long long*)wsb;
    int* flags = (int*)(wsb + FLAGS_BOFF);
    int* myflag = flags + ((g * 8 + w) * 8 + m) * 16;
    float cpriv = 0.f;

#define SLOT_R(n) (board + (size_t)((((n - 1) & 7) * 32 + g)) * 512)
#define SLOT_W(n) (board + (size_t)(((n & 7) * 32 + g)) * 512)
#define POST_FLAG(n) do { \
        asm volatile("s_waitcnt vmcnt(0)" ::: "memory"); \
        if (lane == 0) \
            __hip_atomic_store(myflag, (n) + 1, __ATOMIC_RELAXED, \
                               __HIP_MEMORY_SCOPE_AGENT); \
    } while (0)

    if (w < 4) {
        // ---------------- L1 waves (cls 0..3): tau = n ----------------
        _Float16* Xw = smem + XL1_OFF + w * 1056;
        unsigned short* Xu = (unsigned short*)Xw;
        const int u = w * 64 + lane;
        const int kg = lane & 7;
        for (int n = 0; n < NLOOP; ++n) {
            float xt = 0.f;
            if (kg < 4 && n < TT)
                xt = inp[(size_t)(g * 4 + kg) * TT + n];   // issued early, used late
            wait_cls(flags, g, 0, 4, n, lane);
            if (n < TT) {
                stage<4, 264>(SLOT_R(n), lane * 4, lane * 4, Xu);
                layer_pw<32, 8, 4, K1STR, 264, 0, true>(
                    Wl1, bias1, Xw, SLOT_W(n), w1xl, xt, cpriv, u, lane, m);
            }
            POST_FLAG(n);
            if ((n & 3) == 0 && n > 0)
                wait_cls(flags, g, 4, 2, n - 3, lane);   // throttle vs L2 (h1 ring)
        }
    } else if (w < 6) {
        // ---------------- L2 waves (cls 4,5): tau = n-1 ----------------
        _Float16* Xw = smem + XL2_OFF + (w - 4) * 1568;
        unsigned short* Xu = (unsigned short*)Xw;
        const int u = (w - 4) * 64 + lane;
        for (int n = 0; n < NLOOP; ++n) {
            wait_cls(flags, g, 0, 6, n, lane);           // h1 (cls0-3) + h2 peers (4,5)
            int t2 = n - 1;
            if (t2 >= 0 && t2 < TT) {
                stage<6, 392>(SLOT_R(n), lane * 6, lane * 6, Xu);
                layer_pw<16, 8, 6, K2STR, 392, 256, false>(
                    Wl2, bias2, Xw, SLOT_W(n), w1xl, 0.f, cpriv, u, lane, m);
            }
            POST_FLAG(n);
            if ((n & 3) == 0 && n > 0)
                wait_cls(flags, g, 6, 1, n - 3, lane);   // throttle vs L3 (h2 ring)
        }
    } else if (w == 6) {
        // ------------- w6 (cls 6): L3 (tau=n-2) + head (tau=n-5, m==0) -------------
        _Float16* X3 = smem + XL3_OFF;
        unsigned short* X3u = (unsigned short*)X3;
        _Float16* X5 = smem + XH5_OFF;
        unsigned short* X5u = (unsigned short*)X5;
        for (int n = 0; n < NLOOP; ++n) {
            wait_cls(flags, g, 4, 4, n, lane);           // h2 (4,5) + h3 peers (6) + h5 (7)
            int t3 = n - 2, th = n - 5;
            const unsigned long long* bsrc = SLOT_R(n);
            if (t3 >= 0 && t3 < TT) {
                if (lane < 48) stage<4, 200>(bsrc, 256 + lane * 4, lane * 4, X3u);
                layer_pw<8, 8, 3, K3STR, 200, 384, false>(
                    Wl3, bias3, X3, SLOT_W(n), w1xl, 0.f, cpriv, lane, lane, m);
            }
            if (th >= 0 && m == 0) {
                if (lane >= 48 && lane < 56)
                    stage<2, 24>(bsrc, 480 + (lane - 48) * 2, (lane - 48) * 2, X5u);
                if (lane < 4) {
                    float a = blin_s;
#pragma unroll
                    for (int k = 0; k < 16; ++k)
                        a = fmaf((float)X5[lane * 24 + k], wlin_s[k], a);
                    out[(size_t)(g * 4 + lane) * TT + th] = a;
                }
            }
            POST_FLAG(n);
            // no throttle: w6 and w7 are mutually flag-locked each counter
        }
    } else {
        // ------------- w7 (cls 7): L4 (tau=n-3) + L5 (tau=n-4) -------------
        _Float16* X4 = smem + XL4_OFF;
        unsigned short* X4u = (unsigned short*)X4;
        _Float16* X5i = smem + XL5_OFF;
        unsigned short* X5iu = (unsigned short*)X5i;
        for (int n = 0; n < NLOOP; ++n) {
            wait_cls(flags, g, 6, 2, n, lane);           // h3 (6) + h4/h5 peers (7)
            int t4 = n - 3, t5 = n - 4;
            const unsigned long long* bsrc = SLOT_R(n);
            if (t4 >= 0 && t4 < TT && lane < 24)
                stage<4, 136>(bsrc, 384 + lane * 4, lane * 4, X4u);
            if (t5 >= 0 && t5 < TT && lane >= 24 && lane < 48)
                stage<2, 72>(bsrc, 448 + (lane - 24) * 2, (lane - 24) * 2, X5iu);
            if (t4 >= 0 && t4 < TT && lane < 32)
                layer_pw<4, 8, 2, K4STR, 136, 448, false>(
                    Wl4, bias4, X4, SLOT_W(n), w1xl, 0.f, cpriv, lane, lane, m);
            if (t5 >= 0 && t5 < TT && lane >= 32 && lane < 48)
                layer_pw<2, 8, 1, K5STR, 72, 480, false>(
                    Wl5, bias5, X5i, SLOT_W(n), w1xl, 0.f, cpriv, lane - 32, lane, m);
            POST_FLAG(n);
        }
    }
#undef SLOT_R
#undef SLOT_W
#undef POST_FLAG
}

extern "C" void kernel_launch(void* const* d_in, const int* in_sizes, int n_in,
                              void* d_out, int out_size, void* d_ws, size_t ws_size,
                              hipStream_t stream) {
    const float* p[23];
    for (int i = 0; i < 23 && i < n_in; ++i) p[i] = (const float*)d_in[i];

    (void)hipFuncSetAttribute((const void*)lstm_pw,
                              hipFuncAttributeMaxDynamicSharedMemorySize,
                              LDS_BYTES);

    prep_zero<<<dim3((ZERO_F4 + 255) / 256), dim3(256), 0, stream>>>((float4*)d_ws);

    // ~151 KB dynamic + ~1.6 KB static LDS -> 1 block/CU; grid 256 = CU count ->
    // all 32 groups x 8 members co-resident (required for the flag dataflow).
    lstm_pw<<<dim3(256), dim3(512), LDS_BYTES, stream>>>(
        p[0],
        p[1],  p[2],  p[3],  p[4],
        p[5],  p[6],  p[7],  p[8],
        p[9],  p[10], p[11], p[12],
        p[13], p[14], p[15], p[16],
        p[17], p[18], p[19], p[20],
        p[21], p[22],
        (float*)d_out, (char*)d_ws);
}

// Round 10
// 10951.160 us; speedup vs baseline: 1.4577x; 1.3001x over previous
//
#include <hip/hip_runtime.h>
#include <math.h>

#define TT 2048
#define NSTEP 2053   // 2048 + 4 pipeline fill + 1 head drain

typedef _Float16 half2v __attribute__((ext_vector_type(2)));
typedef _Float16 half8v __attribute__((ext_vector_type(8)));

#if defined(__has_builtin)
#if __has_builtin(__builtin_amdgcn_fdot2)
#define HAVE_FDOT2 1
#endif
#endif

__device__ __forceinline__ float fdot2f(half2v a, half2v b, float c) {
#ifdef HAVE_FDOT2
    return __builtin_amdgcn_fdot2(a, b, c, false);
#else
    return c + (float)a.x * (float)b.x + (float)a.y * (float)b.y;
#endif
}
__device__ __forceinline__ half2v h2at(half8v v, int m) {
    half2v r; r.x = v[2 * m]; r.y = v[2 * m + 1]; return r;
}
__device__ __forceinline__ float sigf(float x) { return 1.0f / (1.0f + __expf(-x)); }
__device__ __forceinline__ float tanh_f(float x) {
    float t = __expf(fminf(2.0f * x, 30.0f));
    return (t - 1.0f) / (t + 1.0f);
}

// ---- d_ws layout (bytes) ----
// [0, 262144)        board: u64 [2 parity][32 group][512 h] (u64 = 4 batch fp16)
// [262144, +32768)   flags: int [32 group][8 member] stride 32 ints (128B lines)
#define FLAGS_BOFF 262144
#define ZERO_F4    18432     // float4 count covering board+flags

// ---- dynamic LDS (halves); R6-proven strides (stride%64==32 -> 2-way alias, free)
#define K1STR 264
#define K2STR 392
#define K3STR 200
#define K4STR 104
#define K5STR 72
#define XSTR  520
#define XPAR  2080           // 4 batches x XSTR, per parity
#define W1_OFF 0             // 128 x 264 = 33792
#define W2_OFF 33792         // 64 x 392  = 25088
#define W3_OFF 58880         // 32 x 200  = 6400
#define W4_OFF 65280         // 16 x 104  = 1664
#define W5_OFF 66944         // 8 x 72    = 576
#define X_OFF  67520         // 2 parity x 2080
#define LDS_HALVES 71680
#define LDS_BYTES  143360

__global__ __launch_bounds__(256)
void prep_zero(float4* ws) {
    int idx = blockIdx.x * 256 + threadIdx.x;
    if (idx < ZERO_F4) ws[idx] = make_float4(0.f, 0.f, 0.f, 0.f);
}

// R6-proven layer slice: RG h-units, rows r = rg + RG*i (gate i), KG-way k-split,
// J iters of 8k. Butterfly over kg; lanes kg<4 own batch kg (c in register);
// lane kg==0 stores packed u64 (4 batches fp16) to board. No fences anywhere.
template<int RG, int KG, int J, int KOFF, int KSTR, int HBASE, bool ISL1>
__device__ __forceinline__ void layer_g8(
    const _Float16* __restrict__ W, const float* __restrict__ bias,
    const _Float16* __restrict__ Xs,
    unsigned long long* __restrict__ bdst,
    const float* __restrict__ w1xl, const float* __restrict__ xinl, int xoff,
    float& cpriv, int u, int lane, int m)
{
    const int kg = u & (KG - 1);
    const int rg = u / KG;

    float acc[4][4];
#pragma unroll
    for (int i = 0; i < 4; ++i)
#pragma unroll
        for (int j = 0; j < 4; ++j) acc[i][j] = 0.f;

#pragma unroll
    for (int jj = 0; jj < J; ++jj) {
        const int kk = kg * 8 + jj * (KG * 8);
        half8v xv[4], wv[4];
#pragma unroll
        for (int j = 0; j < 4; ++j)
            xv[j] = *(const half8v*)(Xs + j * XSTR + KOFF + kk);
#pragma unroll
        for (int i = 0; i < 4; ++i)
            wv[i] = *(const half8v*)(W + (rg + RG * i) * KSTR + kk);
#pragma unroll
        for (int i = 0; i < 4; ++i)
#pragma unroll
            for (int j = 0; j < 4; ++j)
#pragma unroll
                for (int mm = 0; mm < 4; ++mm)
                    acc[i][j] = fdot2f(h2at(wv[i], mm), h2at(xv[j], mm), acc[i][j]);
    }

#pragma unroll
    for (int d = 1; d < KG; d <<= 1)
#pragma unroll
        for (int i = 0; i < 4; ++i)
#pragma unroll
            for (int j = 0; j < 4; ++j)
                acc[i][j] += __shfl_xor(acc[i][j], d, 64);

    float h = 0.f;
    if (kg < 4) {
        const int j = kg;
        float g0 = acc[0][j] + bias[rg];
        float g1 = acc[1][j] + bias[rg + RG];
        float g2 = acc[2][j] + bias[rg + 2 * RG];
        float g3 = acc[3][j] + bias[rg + 3 * RG];
        if (ISL1) {
            float xt = xinl[j * 64 + xoff];
            g0 = fmaf(w1xl[rg], xt, g0);
            g1 = fmaf(w1xl[rg + RG], xt, g1);
            g2 = fmaf(w1xl[rg + 2 * RG], xt, g2);
            g3 = fmaf(w1xl[rg + 3 * RG], xt, g3);
        }
        float ig = sigf(g0), fg = sigf(g1), gg = tanh_f(g2), og = sigf(g3);
        float cn = fmaf(fg, cpriv, ig * gg);
        cpriv = cn;
        h = og * tanh_f(cn);
    }
    union { _Float16 hf; unsigned short us; } cv;
    cv.hf = (_Float16)h;
    const int base = lane & ~(KG - 1);
    unsigned long long p0 = (unsigned short)__shfl((int)cv.us, base + 0, 64);
    unsigned long long p1 = (unsigned short)__shfl((int)cv.us, base + 1, 64);
    unsigned long long p2 = (unsigned short)__shfl((int)cv.us, base + 2, 64);
    unsigned long long p3 = (unsigned short)__shfl((int)cv.us, base + 3, 64);
    if (kg == 0) {
        unsigned long long packed = p0 | (p1 << 16) | (p2 << 32) | (p3 << 48);
        __hip_atomic_store(bdst + (HBASE + m * RG + rg), packed,
                           __ATOMIC_RELAXED, __HIP_MEMORY_SCOPE_AGENT);
    }
}

__global__ __launch_bounds__(512)
void lstm_fg(const float* __restrict__ inp,
             const float* __restrict__ w1ih, const float* __restrict__ w1hh,
             const float* __restrict__ b1ih, const float* __restrict__ b1hh,
             const float* __restrict__ w2ih, const float* __restrict__ w2hh,
             const float* __restrict__ b2ih, const float* __restrict__ b2hh,
             const float* __restrict__ w3ih, const float* __restrict__ w3hh,
             const float* __restrict__ b3ih, const float* __restrict__ b3hh,
             const float* __restrict__ w4ih, const float* __restrict__ w4hh,
             const float* __restrict__ b4ih, const float* __restrict__ b4hh,
             const float* __restrict__ w5ih, const float* __restrict__ w5hh,
             const float* __restrict__ b5ih, const float* __restrict__ b5hh,
             const float* __restrict__ wlin, const float* __restrict__ blin,
             float* __restrict__ out, char* __restrict__ wsb)
{
    extern __shared__ __align__(16) _Float16 smem[];
    _Float16* Wl1 = smem + W1_OFF;
    _Float16* Wl2 = smem + W2_OFF;
    _Float16* Wl3 = smem + W3_OFF;
    _Float16* Wl4 = smem + W4_OFF;
    _Float16* Wl5 = smem + W5_OFF;

    __shared__ float Xin[256];                 // [4 b][64 t] input chunk
    __shared__ float bias1[128], bias2[64], bias3[32], bias4[16], bias5[8];
    __shared__ float w1xl[128], wlin_s[16], blin_s;
    __shared__ int arrive[2];                  // per-parity wave arrival counter

    const int tid = threadIdx.x;
    const int g = blockIdx.x & 31;     // group (members {g,g+32,..}: same mod-8 class)
    const int m = blockIdx.x >> 5;     // member 0..7
    const int w = tid >> 6;            // wave 0..7
    const int lane = tid & 63;

    // ---- init: stage fp16 weight shards into LDS (R6-identical) ----
    for (int idx = tid; idx < 128 * 256; idx += 512) {
        int r = idx >> 8, k = idx & 255;
        int i = r >> 5, rg = r & 31;
        int grow = i * 256 + m * 32 + rg;
        Wl1[r * K1STR + k] = (_Float16)w1hh[grow * 256 + k];
    }
    for (int idx = tid; idx < 64 * 384; idx += 512) {
        int r = idx / 384, k = idx - r * 384;
        int i = r >> 4, rg = r & 15;
        int grow = i * 128 + m * 16 + rg;
        float v = (k < 256) ? w2ih[grow * 256 + k] : w2hh[grow * 128 + (k - 256)];
        Wl2[r * K2STR + k] = (_Float16)v;
    }
    for (int idx = tid; idx < 32 * 192; idx += 512) {
        int r = idx / 192, k = idx - r * 192;
        int i = r >> 3, rg = r & 7;
        int grow = i * 64 + m * 8 + rg;
        float v = (k < 128) ? w3ih[grow * 128 + k] : w3hh[grow * 64 + (k - 128)];
        Wl3[r * K3STR + k] = (_Float16)v;
    }
    for (int idx = tid; idx < 16 * 96; idx += 512) {
        int r = idx / 96, k = idx - r * 96;
        int i = r >> 2, rg = r & 3;
        int grow = i * 32 + m * 4 + rg;
        float v = (k < 64) ? w4ih[grow * 64 + k] : w4hh[grow * 32 + (k - 64)];
        Wl4[r * K4STR + k] = (_Float16)v;
    }
    for (int idx = tid; idx < 8 * 64; idx += 512) {      // L5 k-padded to 64
        int r = idx >> 6, k = idx & 63;
        int i = r >> 1, rg = r & 1;
        int grow = i * 16 + m * 2 + rg;
        float v = (k < 32) ? w5ih[grow * 32 + k]
                           : (k < 48 ? w5hh[grow * 16 + (k - 32)] : 0.f);
        Wl5[r * K5STR + k] = (_Float16)v;
    }
    for (int idx = tid; idx < 2 * XPAR; idx += 512)
        smem[X_OFF + idx] = (_Float16)0.f;     // zero both parities (incl. k>=496 pad)

    if (tid < 128) {
        int i = tid >> 5, rg = tid & 31;
        int grow = i * 256 + m * 32 + rg;
        bias1[tid] = b1ih[grow] + b1hh[grow];
        w1xl[tid] = w1ih[grow];
    } else if (tid < 192) {
        int u = tid - 128; int grow = (u >> 4) * 128 + m * 16 + (u & 15);
        bias2[u] = b2ih[grow] + b2hh[grow];
    } else if (tid < 224) {
        int u = tid - 192; int grow = (u >> 3) * 64 + m * 8 + (u & 7);
        bias3[u] = b3ih[grow] + b3hh[grow];
    } else if (tid < 240) {
        int u = tid - 224; int grow = (u >> 2) * 32 + m * 4 + (u & 3);
        bias4[u] = b4ih[grow] + b4hh[grow];
    } else if (tid < 248) {
        int u = tid - 240; int grow = (u >> 1) * 16 + m * 2 + (u & 1);
        bias5[u] = b5ih[grow] + b5hh[grow];
    } else if (tid < 264) {
        wlin_s[tid - 248] = wlin[tid - 248];
    } else if (tid == 264) {
        blin_s = blin[0];
    } else if (tid == 265) {
        arrive[0] = 0; arrive[1] = 0;
    }
    __syncthreads();

    unsigned long long* board = (unsigned long long*)wsb;
    int* flags = (int*)(wsb + FLAGS_BOFF);
    int* myflag = flags + (g * 8 + m) * 32;
    float cpriv = 0.f;

    for (int s = 0; s < NSTEP; ++s) {
        const int pr = (s + 1) & 1, pw = s & 1;
        _Float16* Xp = smem + X_OFF + pw * XPAR;           // stage+compute parity

        // ---- Phase A: wave w polls ONLY member w's flag, then loads its own
        // contiguous 62-u64 slice. 8-way parallel poll+load; stragglers overlap
        // with early members' in-flight loads. Relaxed/fence-free (R6 protocol:
        // producer drained vmcnt before flag post -> LLC serialization).
        {
            const int* fp = flags + (g * 8 + w) * 32;
            while (__hip_atomic_load(fp, __ATOMIC_RELAXED,
                                     __HIP_MEMORY_SCOPE_AGENT) < s)
                __builtin_amdgcn_s_sleep(1);
            asm volatile("" ::: "memory");     // no hoisting loads above the poll
            if (lane < 62) {
                const unsigned long long* bsrc =
                    board + (size_t)((pr * 32 + g)) * 512;
                int k = w * 62 + lane;
                unsigned long long v = __hip_atomic_load(
                    bsrc + k, __ATOMIC_RELAXED, __HIP_MEMORY_SCOPE_AGENT);
                unsigned short* Xu = (unsigned short*)Xp;
                Xu[0 * XSTR + k] = (unsigned short)v;
                Xu[1 * XSTR + k] = (unsigned short)(v >> 16);
                Xu[2 * XSTR + k] = (unsigned short)(v >> 32);
                Xu[3 * XSTR + k] = (unsigned short)(v >> 48);
            }
            if (w == 7 && ((s & 63) == 0) && s < TT && lane < 16) {
                int b = lane >> 2, q = lane & 3;
                *(float4*)(Xin + b * 64 + q * 4) =
                    *(const float4*)(inp + (size_t)(g * 4 + b) * TT + s + q * 4);
            }
        }
        __syncthreads();   // Xs[pw] + Xin staged block-wide

        unsigned long long* bdst = board + (size_t)((pw * 32 + g)) * 512;
        const int xoff = s & 63;

        // ---- Phase B: diagonal layer pipeline (R6-identical math/ranges) ----
        if (tid < 256) {
            if (s < 2048)
                layer_g8<32, 8, 4, 0, K1STR, 0, true>(
                    Wl1, bias1, Xp, bdst, w1xl, Xin, xoff, cpriv, tid, lane, m);
        } else if (tid < 384) {
            if (s >= 1 && s <= 2048)
                layer_g8<16, 8, 6, 0, K2STR, 256, false>(
                    Wl2, bias2, Xp, bdst, w1xl, Xin, 0, cpriv, tid - 256, lane, m);
        } else if (tid < 448) {
            if (s >= 2 && s <= 2049)
                layer_g8<8, 8, 3, 256, K3STR, 384, false>(
                    Wl3, bias3, Xp, bdst, w1xl, Xin, 0, cpriv, tid - 384, lane, m);
        } else if (tid < 464) {
            if (s >= 3 && s <= 2050)
                layer_g8<4, 4, 3, 384, K4STR, 448, false>(
                    Wl4, bias4, Xp, bdst, w1xl, Xin, 0, cpriv, tid - 448, lane, m);
        } else if (tid < 472) {
            if (s >= 4 && s <= 2051)
                layer_g8<2, 4, 2, 448, K5STR, 480, false>(
                    Wl5, bias5, Xp, bdst, w1xl, Xin, 0, cpriv, tid - 464, lane, m);
        } else if (tid < 476) {
            if (m == 0 && s >= 5) {
                int b = tid - 472;
                float a = blin_s;
#pragma unroll
                for (int j = 0; j < 16; ++j)
                    a = fmaf((float)Xp[b * XSTR + 480 + j], wlin_s[j], a);
                out[(size_t)(g * 4 + b) * TT + (s - 5)] = a;
            }
        }

        // ---- Phase C: per-wave drain + LDS arrive; 8th wave posts global flag.
        // No trailing barrier: waves proceed straight to next poll. Safe: parity
        // double-buffers Xs/arrive; the Phase-A barrier bounds local skew to 1.
        asm volatile("s_waitcnt vmcnt(0)" ::: "memory");
        if (lane == 0) {
            int old = __hip_atomic_fetch_add(&arrive[pw], 1, __ATOMIC_RELAXED,
                                             __HIP_MEMORY_SCOPE_WORKGROUP);
            if (old == 7) {
                __hip_atomic_store(&arrive[pw], 0, __ATOMIC_RELAXED,
                                   __HIP_MEMORY_SCOPE_WORKGROUP);
                __hip_atomic_store(myflag, s + 1, __ATOMIC_RELAXED,
                                   __HIP_MEMORY_SCOPE_AGENT);
            }
        }
    }
}

extern "C" void kernel_launch(void* const* d_in, const int* in_sizes, int n_in,
                              void* d_out, int out_size, void* d_ws, size_t ws_size,
                              hipStream_t stream) {
    const float* p[23];
    for (int i = 0; i < 23 && i < n_in; ++i) p[i] = (const float*)d_in[i];

    (void)hipFuncSetAttribute((const void*)lstm_fg,
                              hipFuncAttributeMaxDynamicSharedMemorySize,
                              LDS_BYTES);

    prep_zero<<<dim3((ZERO_F4 + 255) / 256), dim3(256), 0, stream>>>((float4*)d_ws);

    // ~140 KB dynamic + ~2.6 KB static LDS -> 1 block/CU; grid 256 = CU count ->
    // all 32 groups x 8 members co-resident (required for the flag protocol).
    lstm_fg<<<dim3(256), dim3(512), LDS_BYTES, stream>>>(
        p[0],
        p[1],  p[2],  p[3],  p[4],
        p[5],  p[6],  p[7],  p[8],
        p[9],  p[10], p[11], p[12],
        p[13], p[14], p[15], p[16],
        p[17], p[18], p[19], p[20],
        p[21], p[22],
        (float*)d_out, (char*)d_ws);
}